// Round 8
// baseline (317.389 us; speedup 1.0000x reference)
//
#include <hip/hip_runtime.h>

typedef _Float16 f16_t;
typedef _Float16 f16x2 __attribute__((ext_vector_type(2)));
typedef _Float16 f16x8 __attribute__((ext_vector_type(8)));
typedef float floatx4 __attribute__((ext_vector_type(4)));
typedef unsigned int u32;
typedef unsigned int u32x2 __attribute__((ext_vector_type(2)));
typedef unsigned int u32x4 __attribute__((ext_vector_type(4)));
typedef const __attribute__((address_space(1))) unsigned int* gptr_as1;
typedef __attribute__((address_space(3))) unsigned int* lptr_as3;

#define B_ 8
#define C_ 512
#define L_ 2048
#define D_ 1024
#define H_ 16

static __device__ __forceinline__ f16x2 bc2(u32 v) { return __builtin_bit_cast(f16x2, v); }
static __device__ __forceinline__ u32 cb2(f16x2 v) { return __builtin_bit_cast(u32, v); }

#define SCHEDB() __builtin_amdgcn_sched_barrier(0)

// ---------------------------------------------------------------------------
// Transpose + f32->f16 convert: in (R,C) f32 -> out (C,R) f16, batched z.
// (outputs NOT marked nt: xT is the QKV B-panel, we want it L2-resident)
// ---------------------------------------------------------------------------
__global__ __launch_bounds__(256) void _MSA1_ktransf2h(const float* __restrict__ in,
                                                       f16_t* __restrict__ out,
                                                       int R, int C) {
  size_t zoff = (size_t)blockIdx.z * R * C;
  in += zoff; out += zoff;
  __shared__ f16_t tile[64][65];
  int r0 = blockIdx.y * 64, c0 = blockIdx.x * 64;
  int t = threadIdx.x;
  #pragma unroll
  for (int i = 0; i < 16; ++i) {
    int idx = t + i * 256;
    int r = idx >> 6, c = idx & 63;
    tile[c][r] = (f16_t)in[(size_t)(r0 + r) * C + (c0 + c)];
  }
  __syncthreads();
  #pragma unroll
  for (int i = 0; i < 16; ++i) {
    int idx = t + i * 256;
    int r = idx >> 6, c = idx & 63;
    out[(size_t)(c0 + r) * R + (r0 + c)] = tile[r][c];
  }
}

// ---------------------------------------------------------------------------
// Fused prep: all 4 weight transposes (f32->f16) + bias concat, one launch.
// ---------------------------------------------------------------------------
__global__ __launch_bounds__(256) void _MSA1_kprep(
    const float* __restrict__ wq, const float* __restrict__ wk,
    const float* __restrict__ wv, const float* __restrict__ wo,
    const float* __restrict__ bq, const float* __restrict__ bk,
    const float* __restrict__ bv,
    f16_t* __restrict__ wT3, f16_t* __restrict__ woT, float* __restrict__ bias3) {
  const int x = blockIdx.x, y = blockIdx.y;
  const int t = threadIdx.x;
  if (x == 128) {
    if (y == 0) {
      for (int i = t; i < 1024; i += 256) {
        bias3[i] = bq[i];
        bias3[1024 + i] = bk[i];
        bias3[2048 + i] = bv[i];
      }
    }
    return;
  }
  __shared__ f16_t tile[64][65];
  const float* in; f16_t* out; int R, C, r0, c0;
  if (y < 3) {
    R = 512; C = 1024;
    in = (y == 0) ? wq : (y == 1) ? wk : wv;
    out = wT3 + (size_t)y * 524288;
    r0 = (x >> 4) * 64; c0 = (x & 15) * 64;
  } else {
    R = 1024; C = 512;
    in = wo; out = woT;
    r0 = (x >> 3) * 64; c0 = (x & 7) * 64;
  }
  #pragma unroll
  for (int i = 0; i < 16; ++i) {
    int idx = t + i * 256;
    int r = idx >> 6, c = idx & 63;
    tile[c][r] = (f16_t)in[(size_t)(r0 + r) * C + (c0 + c)];
  }
  __syncthreads();
  #pragma unroll
  for (int i = 0; i < 16; ++i) {
    int idx = t + i * 256;
    int r = idx >> 6, c = idx & 63;
    out[(size_t)(c0 + r) * R + (r0 + c)] = tile[r][c];
  }
}

// ---------------------------------------------------------------------------
// kgemm8 (QKV), round-6 best structure REVERTED (72.5us): BM=128, BN=256,
// 512 thr (8 waves 2Mx4N, wave tile 64x64), BK=32, 3 LDS buffers (72 KB),
// STAGE(i+2) at top of iter i, in-loop wait vmcnt(3)+lgkmcnt(0), vmcnt(0)
// only at tail, sched_barrier(0) fences (rule 18).  IDENTITY block mapping.
// Round-7 lesson: 2-buf/48KB regressed (-3%) -- the post-barrier DMA issue
// must land within one MFMA phase (~320cyc < L2/HBM latency); occupancy
// never rose.  Do not re-try.
// v8 delta: qkv epilogue stores are NON-TEMPORAL (nt).  The 98MB output
// stream has zero intra-kernel reuse and was evicting the A/B panels
// (FETCH 53-69MB vs ~20MB ideal = 2-3x refetch).
// ---------------------------------------------------------------------------
template <int K>
__global__ __launch_bounds__(512, 4) void _MSA1_kgemm8(
    const f16_t* __restrict__ A, const f16_t* __restrict__ Bt,
    const float* __restrict__ bias, f16_t* __restrict__ Cd0,
    int M, int N, long sB, long sC) {
  const f16_t* Bz = Bt + (size_t)blockIdx.z * sB;
  const int m0 = blockIdx.y * 128, n0 = blockIdx.x * 256;

  union __align__(16) ShU {
    struct { f16_t As[3][128][32]; f16_t Bs[3][256][32]; } ab;  // 72 KB
    f16_t Ep[64][264];                                           // 67.6 KB
  };
  __shared__ ShU sh;

  const int t = threadIdx.x;
  const int lane = t & 63, w = t >> 6;
  const int wm = w & 1;
  const int mh = wm * 64, nh = (w >> 1) * 64;
  const int fm = lane & 15, fq = lane >> 4;
  // staging source pre-swizzle: slot = (lane&3) ^ (r&3) ^ ((r>>2)&3)
  const int srcswz = ((t & 3) ^ ((t >> 2) & 3) ^ ((t >> 4) & 3)) * 8;
  // frag-read column swizzle: R&3 = fm&3, (R>>2)&3 = (fm>>2)&3  ->  slot fq
  const int colf = ((fq ^ (fm & 3) ^ ((fm >> 2) & 3)) * 8);

  floatx4 acc[4][4];
  #pragma unroll
  for (int i = 0; i < 4; ++i)
    #pragma unroll
    for (int j = 0; j < 4; ++j) {
      floatx4 z4 = {0.f, 0.f, 0.f, 0.f};
      acc[i][j] = z4;
    }

  auto STAGE = [&](int kt, int bi) {
    {                                                  // A: 128 rows, 8 KB
      int r = t >> 2;
      const f16_t* ga = A + (size_t)(m0 + r) * K + kt + srcswz;
      __builtin_amdgcn_global_load_lds((gptr_as1)(const void*)ga,
          (lptr_as3)(void*)((char*)&sh.ab.As[bi][0][0] + t * 16), 16, 0, 0);
    }
    #pragma unroll
    for (int j = 0; j < 2; ++j) {                      // B: 256 rows, 16 KB
      int idx = j * 512 + t;
      int r = idx >> 2;
      const f16_t* gb = Bz + (size_t)(n0 + r) * K + kt + srcswz;
      __builtin_amdgcn_global_load_lds((gptr_as1)(const void*)gb,
          (lptr_as3)(void*)((char*)&sh.ab.Bs[bi][0][0] + idx * 16), 16, 0, 0);
    }
  };

  // prologue: stage tiles 0,1; wait tile 0 (3 newest stay in flight)
  STAGE(0, 0);
  STAGE(32, 1);
  SCHEDB();
  asm volatile("s_waitcnt vmcnt(3)" ::: "memory");
  __builtin_amdgcn_s_barrier();
  SCHEDB();

  int bcur = 0;
  for (int kt = 0; kt < K; kt += 32) {
    if (kt + 64 < K) {                       // stage tile t+2
      int bi = bcur + 2; if (bi >= 3) bi -= 3;
      STAGE(kt + 64, bi);
    }
    f16x8 af[4], bfr[4];
    #pragma unroll
    for (int mt = 0; mt < 4; ++mt)
      af[mt] = *(const f16x8*)&sh.ab.As[bcur][mh + mt * 16 + fm][colf];
    #pragma unroll
    for (int nt = 0; nt < 4; ++nt)
      bfr[nt] = *(const f16x8*)&sh.ab.Bs[bcur][nh + nt * 16 + fm][colf];
    __builtin_amdgcn_s_setprio(1);
    #pragma unroll
    for (int mt = 0; mt < 4; ++mt)
      #pragma unroll
      for (int nt = 0; nt < 4; ++nt)
        acc[mt][nt] = __builtin_amdgcn_mfma_f32_16x16x32_f16(
            af[mt], bfr[nt], acc[mt][nt], 0, 0, 0);
    __builtin_amdgcn_s_setprio(0);
    if (kt + 32 < K) {
      SCHEDB();
      if (kt + 64 < K)
        asm volatile("s_waitcnt vmcnt(3) lgkmcnt(0)" ::: "memory");
      else
        asm volatile("s_waitcnt vmcnt(0) lgkmcnt(0)" ::: "memory");  // tail
      __builtin_amdgcn_s_barrier();
      SCHEDB();
    }
    bcur = (bcur == 2) ? 0 : bcur + 1;
  }
  __syncthreads();   // full drain before Ep union reuse

  // ---- epilogue: 2 bands of 64 rows via Ep; frag row = fq*4+r, col = fm ----
  f16_t* Cd = Cd0 + (size_t)blockIdx.z * sC;
  #pragma unroll
  for (int p = 0; p < 2; ++p) {
    if (p) __syncthreads();
    if (wm == p) {
      #pragma unroll
      for (int mt = 0; mt < 4; ++mt) {
        float bv4[4];
        #pragma unroll
        for (int r = 0; r < 4; ++r)
          bv4[r] = bias[m0 + p * 64 + mt * 16 + fq * 4 + r];
        #pragma unroll
        for (int nt = 0; nt < 4; ++nt) {
          int col = nh + nt * 16 + fm;
          #pragma unroll
          for (int r = 0; r < 4; ++r) {
            int row = mt * 16 + fq * 4 + r;     // 0..63 within band
            sh.Ep[row][col] = (f16_t)(acc[mt][nt][r] + bv4[r]);
          }
        }
      }
    }
    __syncthreads();
    #pragma unroll
    for (int ii = 0; ii < 8; ++ii) {
      int chunk = ii * 512 + t;          // 4096 x 8B chunks, 64 rows x 64
      int row = chunk >> 6, c8 = chunk & 63;
      u32x2 val = *(const u32x2*)&sh.Ep[row][c8 * 4];
      __builtin_nontemporal_store(val,
          (u32x2*)&Cd[(size_t)(m0 + p * 64 + row) * N + n0 + c8 * 4]);
    }
  }
}

// ---------------------------------------------------------------------------
// GEMM (output projection): 256x128 tile, BK=32, 512 thr / 8 waves (wave
// tile 64x64, acc[4][4]), 3-buffer counted-vmcnt pipeline, vmcnt(3) in-loop.
// Block mapping: IDENTITY (round-7 A/B: z-per-XCD remap cost ~+2.5us here;
// the round-5->6 "+14us" attribution was cross-run noise -- closed).
// v8 delta: f32 output stores NON-TEMPORAL (134MB stream, no reuse).
// ---------------------------------------------------------------------------
template <bool F32OUT, int K>
__global__ __launch_bounds__(512, 2) void _MSA1_kgemm(
    const f16_t* __restrict__ A, const f16_t* __restrict__ Bt,
    const float* __restrict__ bias, void* __restrict__ Cdv,
    int M, int N, long sA, long sB, long sC) {
  A  += (size_t)blockIdx.z * sA;
  Bt += (size_t)blockIdx.z * sB;
  const int m0 = blockIdx.y * 256, n0 = blockIdx.x * 128;

  union __align__(16) ShU {
    struct { f16_t As[3][256][32]; f16_t Bs[3][128][32]; } ab;  // 72 KB
    f16_t Ep[F32OUT ? 1 : 64][132];
  };
  __shared__ ShU sh;

  const int t = threadIdx.x;
  const int lane = t & 63, w = t >> 6;
  const int mh = (w & 3) * 64, nh = (w >> 2) * 64;
  const int fm = lane & 15, fq = lane >> 4;
  const int srcswz = ((t & 3) ^ ((t >> 2) & 3) ^ ((t >> 4) & 3)) * 8;
  const int colf = ((fq ^ (fm & 3) ^ ((fm >> 2) & 3)) * 8);

  floatx4 acc[4][4];
  #pragma unroll
  for (int i = 0; i < 4; ++i)
    #pragma unroll
    for (int j = 0; j < 4; ++j) {
      floatx4 z4 = {0.f, 0.f, 0.f, 0.f};
      acc[i][j] = z4;
    }

  auto STAGE = [&](int kt, int bi) {
    #pragma unroll
    for (int j = 0; j < 2; ++j) {                      // A: 256 rows, 16 KB
      int idx = j * 512 + t;
      int r = idx >> 2;
      const f16_t* ga = A + (size_t)(m0 + r) * K + kt + srcswz;
      __builtin_amdgcn_global_load_lds((gptr_as1)(const void*)ga,
          (lptr_as3)(void*)((char*)&sh.ab.As[bi][0][0] + idx * 16), 16, 0, 0);
    }
    {                                                  // B: 128 rows, 8 KB
      int r = t >> 2;
      const f16_t* gb = Bt + (size_t)(n0 + r) * K + kt + srcswz;
      __builtin_amdgcn_global_load_lds((gptr_as1)(const void*)gb,
          (lptr_as3)(void*)((char*)&sh.ab.Bs[bi][0][0] + t * 16), 16, 0, 0);
    }
  };

  STAGE(0, 0);
  STAGE(32, 1);
  SCHEDB();
  asm volatile("s_waitcnt vmcnt(3)" ::: "memory");
  __builtin_amdgcn_s_barrier();
  SCHEDB();

  int bcur = 0;
  for (int kt = 0; kt < K; kt += 32) {
    if (kt + 64 < K) {
      int bi = bcur + 2; if (bi >= 3) bi -= 3;
      STAGE(kt + 64, bi);
    }
    f16x8 af[4], bfr[4];
    #pragma unroll
    for (int mt = 0; mt < 4; ++mt)
      af[mt] = *(const f16x8*)&sh.ab.As[bcur][mh + mt * 16 + fm][colf];
    #pragma unroll
    for (int nt = 0; nt < 4; ++nt)
      bfr[nt] = *(const f16x8*)&sh.ab.Bs[bcur][nh + nt * 16 + fm][colf];
    __builtin_amdgcn_s_setprio(1);
    #pragma unroll
    for (int mt = 0; mt < 4; ++mt)
      #pragma unroll
      for (int nt = 0; nt < 4; ++nt)
        acc[mt][nt] = __builtin_amdgcn_mfma_f32_16x16x32_f16(
            af[mt], bfr[nt], acc[mt][nt], 0, 0, 0);
    __builtin_amdgcn_s_setprio(0);
    if (kt + 32 < K) {
      SCHEDB();
      if (kt + 64 < K)
        asm volatile("s_waitcnt vmcnt(3) lgkmcnt(0)" ::: "memory");
      else
        asm volatile("s_waitcnt vmcnt(0) lgkmcnt(0)" ::: "memory");
      __builtin_amdgcn_s_barrier();
      SCHEDB();
    }
    bcur = (bcur == 2) ? 0 : bcur + 1;
  }
  __syncthreads();

  if (F32OUT) {
    float* Cd = (float*)Cdv + (size_t)blockIdx.z * sC;
    #pragma unroll
    for (int mt = 0; mt < 4; ++mt) {
      float bv4[4];
      #pragma unroll
      for (int r = 0; r < 4; ++r)
        bv4[r] = bias[m0 + mh + mt * 16 + fq * 4 + r];
      #pragma unroll
      for (int nt = 0; nt < 4; ++nt) {
        int col = n0 + nh + nt * 16 + fm;
        #pragma unroll
        for (int r = 0; r < 4; ++r) {
          int row = m0 + mh + mt * 16 + fq * 4 + r;
          __builtin_nontemporal_store(acc[mt][nt][r] + bv4[r],
                                      &Cd[(size_t)row * N + col]);
        }
      }
    }
  } else {
    // (dead for current instantiations -- kept for template validity)
    f16_t* Cd = (f16_t*)Cdv + (size_t)blockIdx.z * sC;
    #pragma unroll
    for (int p = 0; p < 4; ++p) {
      if (p) __syncthreads();
      if ((w & 1) == (p >> 1)) {
        #pragma unroll
        for (int mt2 = 0; mt2 < 4; ++mt2) {
          float bv4[4];
          #pragma unroll
          for (int r = 0; r < 4; ++r)
            bv4[r] = bias[m0 + p * 64 + mt2 * 16 + fq * 4 + r];
          #pragma unroll
          for (int nt = 0; nt < 4; ++nt) {
            int col = nh + nt * 16 + fm;
            #pragma unroll
            for (int r = 0; r < 4; ++r) {
              int row = mt2 * 16 + fq * 4 + r;
              sh.Ep[row & (F32OUT ? 0 : 63)][col] = (f16_t)(acc[mt2][nt][r] + bv4[r]);
            }
          }
        }
      }
      __syncthreads();
      #pragma unroll
      for (int i = 0; i < 8; ++i) {
        int chunk = i * 256 + (t & 255);
        int row = chunk >> 5, c8 = chunk & 31;
        uint2 val = *(const uint2*)&sh.Ep[row & (F32OUT ? 0 : 63)][c8 * 4];
        *(uint2*)&Cd[(size_t)(m0 + p * 64 + row) * N + n0 + c8 * 4] = val;
      }
    }
  }
}

// ---------------------------------------------------------------------------
// Attention v6: merged interior+edge (per-lane predication), fused faithful-
// reshape transpose store.  v8: final att2T store non-temporal (33.5MB; its
// consumer runs on a different XCD so L2 retention buys nothing).
// ---------------------------------------------------------------------------
__global__ __launch_bounds__(256) void _MSA1_kattn6(const f16_t* __restrict__ qkv,
                                                    f16_t* __restrict__ attT) {
  const int t = threadIdx.x;
  const int lane = t & 63;
  const int wid = __builtin_amdgcn_readfirstlane(t >> 6);
  const int hb = blockIdx.x;
  const int h = hb & 15, b = hb >> 4;
  const int chi = blockIdx.y;                 // l-chunk 0..7
  const int lbase = chi * 256;
  const int l0 = lbase + lane * 4;
  const size_t plane = (size_t)D_ * L_;
  const f16_t* base = qkv + (size_t)b * 3 * plane;

  __shared__ uint2 sred[4][3][64];
  __shared__ __align__(16) f16_t tile2[2048][8];

  const f16_t* qp = base + (size_t)(h * 64 + wid * 16) * L_ + l0;
  const f16_t* kpl = base + plane;
  const f16_t* vpl = base + 2 * plane;
  const int g0 = h * 192 + wid * 48;

  f16x2 sLo[3], sHi[3];
  #pragma unroll
  for (int w = 0; w < 3; ++w) { f16x2 z = {(f16_t)0, (f16_t)0}; sLo[w] = z; sHi[w] = z; }

  #pragma unroll
  for (int dd = 0; dd < 16; ++dd) {
    uint2 qw = *(const uint2*)(qp + (size_t)dd * L_);
    f16x2 qlo = bc2(qw.x), qhi = bc2(qw.y);
    #pragma unroll
    for (int w = 0; w < 3; ++w) {
      int g = g0 + 3 * dd + w;
      int c = g & 1023;
      int o = (g >> 10) - 1;
      uint2 kw = *(const uint2*)(kpl + (size_t)c * L_ + (l0 + o));
      if (o < 0 && l0 == 0) kw.x &= 0xFFFF0000u;
      if (o > 0 && l0 == 2044) kw.y &= 0x0000FFFFu;
      sLo[w] = bc2(kw.x) * qlo + sLo[w];
      sHi[w] = bc2(kw.y) * qhi + sHi[w];
    }
  }
  #pragma unroll
  for (int w = 0; w < 3; ++w) {
    uint2 v; v.x = cb2(sLo[w]); v.y = cb2(sHi[w]);
    sred[wid][w][lane] = v;
  }
  __syncthreads();

  float sc[4][3];
  #pragma unroll
  for (int j = 0; j < 3; ++j) {
    uint2 r0 = sred[0][j][lane], r1 = sred[1][j][lane];
    uint2 r2 = sred[2][j][lane], r3 = sred[3][j][lane];
    f16x2 lo = (bc2(r0.x) + bc2(r1.x)) + (bc2(r2.x) + bc2(r3.x));
    f16x2 hi = (bc2(r0.y) + bc2(r1.y)) + (bc2(r2.y) + bc2(r3.y));
    sc[0][j] = (float)lo.x * 0.125f;
    sc[1][j] = (float)lo.y * 0.125f;
    sc[2][j] = (float)hi.x * 0.125f;
    sc[3][j] = (float)hi.y * 0.125f;
  }
  f16_t ef[4][3];
  #pragma unroll
  for (int li = 0; li < 4; ++li) {
    float mx = fmaxf(sc[li][0], fmaxf(sc[li][1], sc[li][2]));
    float e0 = __expf(sc[li][0] - mx), e1 = __expf(sc[li][1] - mx), e2 = __expf(sc[li][2] - mx);
    float inv = 1.f / (e0 + e1 + e2);
    ef[li][0] = (f16_t)(e0 * inv); ef[li][1] = (f16_t)(e1 * inv); ef[li][2] = (f16_t)(e2 * inv);
  }
  f16x2 eLo[3], eHi[3];
  #pragma unroll
  for (int w = 0; w < 3; ++w) {
    f16x2 a = {ef[0][w], ef[1][w]}; eLo[w] = a;
    f16x2 b2 = {ef[2][w], ef[3][w]}; eHi[w] = b2;
  }

  const int llb = (lane & 7) * 256 + wid * 16;
  const int jcol = lane >> 3;
  #pragma unroll
  for (int dd = 0; dd < 16; ++dd) {
    f16x2 aLo = {(f16_t)0, (f16_t)0}, aHi = {(f16_t)0, (f16_t)0};
    #pragma unroll
    for (int w = 0; w < 3; ++w) {
      int g = g0 + 3 * dd + w;
      int c = g & 1023;
      int o = (g >> 10) - 1;
      uint2 vw = *(const uint2*)(vpl + (size_t)c * L_ + (l0 + o));
      if (o < 0 && l0 == 0) vw.x &= 0xFFFF0000u;
      if (o > 0 && l0 == 2044) vw.y &= 0x0000FFFFu;
      aLo = bc2(vw.x) * eLo[w] + aLo;
      aHi = bc2(vw.y) * eHi[w] + aHi;
    }
    const int llq = llb + dd;
    tile2[llq +   0][jcol] = aLo.x;
    tile2[llq +  64][jcol] = aLo.y;
    tile2[llq + 128][jcol] = aHi.x;
    tile2[llq + 192][jcol] = aHi.y;
  }
  __syncthreads();

  f16_t* ob = attT + (size_t)b * L_ * D_ + h * 64 + chi * 8;
  #pragma unroll
  for (int i = 0; i < 8; ++i) {
    int ll = i * 256 + t;
    u32x4 val = *(const u32x4*)&tile2[ll][0];
    __builtin_nontemporal_store(val, (u32x4*)(ob + (size_t)ll * D_));
  }
}

// ---------------------------------------------------------------------------
extern "C" void kernel_launch(void* const* d_in, const int* in_sizes, int n_in,
                              void* d_out, int out_size, void* d_ws, size_t ws_size,
                              hipStream_t stream) {
  (void)in_sizes; (void)n_in; (void)out_size;
  const float* x  = (const float*)d_in[0];
  const float* wq = (const float*)d_in[1];
  const float* bq = (const float*)d_in[2];
  const float* wk = (const float*)d_in[3];
  const float* bk = (const float*)d_in[4];
  const float* wv = (const float*)d_in[5];
  const float* bv = (const float*)d_in[6];
  const float* wo = (const float*)d_in[7];
  const float* bo = (const float*)d_in[8];
  float* out = (float*)d_out;
  char* ws = (char*)d_ws;

  f16_t* wT3   = (f16_t*)(ws);                 // 3x(1024x512) f16 = 3,145,728 B
  f16_t* woT   = (f16_t*)(ws + 3145728);       // (512x1024)  f16 = 1,048,576 B
  float* bias3 = (float*) (ws + 4194304);      // 3072 f32 (pad to 16,384)
  const size_t SHARED_END = 4210688;

  _MSA1_kprep<<<dim3(129, 4), dim3(256), 0, stream>>>(
      wq, wk, wv, wo, bq, bk, bv, wT3, woT, bias3);

  if (ws_size >= 155205632ull) {
    // ---------- batched-z path: xT 16.7MB + qkv 100.7MB + att2T 33.5MB ----
    f16_t* xT    = (f16_t*)(ws + SHARED_END);
    f16_t* qkv   = xT + 8388608ull;
    f16_t* att2T = qkv + 50331648ull;

    _MSA1_ktransf2h<<<dim3(32, 8, B_), dim3(256), 0, stream>>>(x, xT, 512, 2048);
    _MSA1_kgemm8<512><<<dim3(8, 24, B_), dim3(512), 0, stream>>>(
        wT3, xT, bias3, qkv, 3072, 2048,
        (long)(2048 * 512), (long)(3072 * 2048));
    _MSA1_kattn6<<<dim3(128, 8), dim3(256), 0, stream>>>(qkv, att2T);
    _MSA1_kgemm<true, 1024><<<dim3(16, 2, B_), dim3(512), 0, stream>>>(
        woT, att2T, bo, out, 512, 2048,
        0L, (long)(2048 * 1024), (long)(512 * 2048));
  } else {
    // ---------- per-batch slab path ----------
    f16_t* xTb    = (f16_t*)(ws + SHARED_END);
    f16_t* qkvb   = xTb + 1048576ull;
    f16_t* att2Tb = qkvb + 6291456ull;
    for (int b = 0; b < B_; ++b) {
      const float* xb = x + (size_t)b * C_ * L_;
      _MSA1_ktransf2h<<<dim3(32, 8, 1), dim3(256), 0, stream>>>(xb, xTb, 512, 2048);
      _MSA1_kgemm8<512><<<dim3(8, 24, 1), dim3(512), 0, stream>>>(
          wT3, xTb, bias3, qkvb, 3072, 2048, 0L, 0L);
      _MSA1_kattn6<<<dim3(16, 8), dim3(256), 0, stream>>>(qkvb, att2Tb);
      _MSA1_kgemm<true, 1024><<<dim3(16, 2, 1), dim3(512), 0, stream>>>(
          woT, att2Tb, bo, out + (size_t)b * C_ * L_, 512, 2048, 0L, 0L, 0L);
    }
  }
}

// Round 9
// 257.879 us; speedup vs baseline: 1.2308x; 1.2308x over previous
//
#include <hip/hip_runtime.h>

typedef _Float16 f16_t;
typedef _Float16 f16x2 __attribute__((ext_vector_type(2)));
typedef _Float16 f16x8 __attribute__((ext_vector_type(8)));
typedef float floatx4 __attribute__((ext_vector_type(4)));
typedef unsigned int u32;
typedef const __attribute__((address_space(1))) unsigned int* gptr_as1;
typedef __attribute__((address_space(3))) unsigned int* lptr_as3;

#define B_ 8
#define C_ 512
#define L_ 2048
#define D_ 1024
#define H_ 16

static __device__ __forceinline__ f16x2 bc2(u32 v) { return __builtin_bit_cast(f16x2, v); }
static __device__ __forceinline__ u32 cb2(f16x2 v) { return __builtin_bit_cast(u32, v); }

#define SCHEDB() __builtin_amdgcn_sched_barrier(0)

// ---------------------------------------------------------------------------
// Transpose + f32->f16 convert: in (R,C) f32 -> out (C,R) f16, batched z.
// ---------------------------------------------------------------------------
__global__ __launch_bounds__(256) void _MSA1_ktransf2h(const float* __restrict__ in,
                                                       f16_t* __restrict__ out,
                                                       int R, int C) {
  size_t zoff = (size_t)blockIdx.z * R * C;
  in += zoff; out += zoff;
  __shared__ f16_t tile[64][65];
  int r0 = blockIdx.y * 64, c0 = blockIdx.x * 64;
  int t = threadIdx.x;
  #pragma unroll
  for (int i = 0; i < 16; ++i) {
    int idx = t + i * 256;
    int r = idx >> 6, c = idx & 63;
    tile[c][r] = (f16_t)in[(size_t)(r0 + r) * C + (c0 + c)];
  }
  __syncthreads();
  #pragma unroll
  for (int i = 0; i < 16; ++i) {
    int idx = t + i * 256;
    int r = idx >> 6, c = idx & 63;
    out[(size_t)(c0 + r) * R + (r0 + c)] = tile[r][c];
  }
}

// ---------------------------------------------------------------------------
// Fused prep: all 4 weight transposes (f32->f16) + bias concat, one launch.
// ---------------------------------------------------------------------------
__global__ __launch_bounds__(256) void _MSA1_kprep(
    const float* __restrict__ wq, const float* __restrict__ wk,
    const float* __restrict__ wv, const float* __restrict__ wo,
    const float* __restrict__ bq, const float* __restrict__ bk,
    const float* __restrict__ bv,
    f16_t* __restrict__ wT3, f16_t* __restrict__ woT, float* __restrict__ bias3) {
  const int x = blockIdx.x, y = blockIdx.y;
  const int t = threadIdx.x;
  if (x == 128) {
    if (y == 0) {
      for (int i = t; i < 1024; i += 256) {
        bias3[i] = bq[i];
        bias3[1024 + i] = bk[i];
        bias3[2048 + i] = bv[i];
      }
    }
    return;
  }
  __shared__ f16_t tile[64][65];
  const float* in; f16_t* out; int R, C, r0, c0;
  if (y < 3) {
    R = 512; C = 1024;
    in = (y == 0) ? wq : (y == 1) ? wk : wv;
    out = wT3 + (size_t)y * 524288;
    r0 = (x >> 4) * 64; c0 = (x & 15) * 64;
  } else {
    R = 1024; C = 512;
    in = wo; out = woT;
    r0 = (x >> 3) * 64; c0 = (x & 7) * 64;
  }
  #pragma unroll
  for (int i = 0; i < 16; ++i) {
    int idx = t + i * 256;
    int r = idx >> 6, c = idx & 63;
    tile[c][r] = (f16_t)in[(size_t)(r0 + r) * C + (c0 + c)];
  }
  __syncthreads();
  #pragma unroll
  for (int i = 0; i < 16; ++i) {
    int idx = t + i * 256;
    int r = idx >> 6, c = idx & 63;
    out[(size_t)(c0 + r) * R + (r0 + c)] = tile[r][c];
  }
}

// ---------------------------------------------------------------------------
// kgemm8 (QKV) -- round-6 best structure (72.5us): BM=128, BN=256, 512 thr
// (8 waves 2Mx4N, wave tile 64x64), BK=32, 3 LDS buffers (72 KB), STAGE(i+2)
// at top of iter i, in-loop wait vmcnt(3)+lgkmcnt(0), vmcnt(0) only at tail,
// sched_barrier(0) fences (rule 18).  IDENTITY block mapping.
// Round-8 lesson (do NOT re-try): nt/evict-first on the qkv epilogue store
// evicted qkv from L3; the attn consumer re-read 114.8MB from HBM and
// DOUBLED its time (60->122us).  Producer->consumer L3 residency is worth
// ~60us in this pipeline; only terminal tensors may use nt.
// Round-7 lesson: 2-buf/48KB regressed (post-barrier DMA can't land within
// one MFMA phase).  Round-5 lesson: z-per-XCD remap thrashes here.
// ---------------------------------------------------------------------------
template <int K>
__global__ __launch_bounds__(512, 4) void _MSA1_kgemm8(
    const f16_t* __restrict__ A, const f16_t* __restrict__ Bt,
    const float* __restrict__ bias, f16_t* __restrict__ Cd0,
    int M, int N, long sB, long sC) {
  const f16_t* Bz = Bt + (size_t)blockIdx.z * sB;
  const int m0 = blockIdx.y * 128, n0 = blockIdx.x * 256;

  union __align__(16) ShU {
    struct { f16_t As[3][128][32]; f16_t Bs[3][256][32]; } ab;  // 72 KB
    f16_t Ep[64][264];                                           // 67.6 KB
  };
  __shared__ ShU sh;

  const int t = threadIdx.x;
  const int lane = t & 63, w = t >> 6;
  const int wm = w & 1;
  const int mh = wm * 64, nh = (w >> 1) * 64;
  const int fm = lane & 15, fq = lane >> 4;
  // staging source pre-swizzle: slot = (lane&3) ^ (r&3) ^ ((r>>2)&3)
  const int srcswz = ((t & 3) ^ ((t >> 2) & 3) ^ ((t >> 4) & 3)) * 8;
  // frag-read column swizzle: R&3 = fm&3, (R>>2)&3 = (fm>>2)&3  ->  slot fq
  const int colf = ((fq ^ (fm & 3) ^ ((fm >> 2) & 3)) * 8);

  floatx4 acc[4][4];
  #pragma unroll
  for (int i = 0; i < 4; ++i)
    #pragma unroll
    for (int j = 0; j < 4; ++j) {
      floatx4 z4 = {0.f, 0.f, 0.f, 0.f};
      acc[i][j] = z4;
    }

  auto STAGE = [&](int kt, int bi) {
    {                                                  // A: 128 rows, 8 KB
      int r = t >> 2;
      const f16_t* ga = A + (size_t)(m0 + r) * K + kt + srcswz;
      __builtin_amdgcn_global_load_lds((gptr_as1)(const void*)ga,
          (lptr_as3)(void*)((char*)&sh.ab.As[bi][0][0] + t * 16), 16, 0, 0);
    }
    #pragma unroll
    for (int j = 0; j < 2; ++j) {                      // B: 256 rows, 16 KB
      int idx = j * 512 + t;
      int r = idx >> 2;
      const f16_t* gb = Bz + (size_t)(n0 + r) * K + kt + srcswz;
      __builtin_amdgcn_global_load_lds((gptr_as1)(const void*)gb,
          (lptr_as3)(void*)((char*)&sh.ab.Bs[bi][0][0] + idx * 16), 16, 0, 0);
    }
  };

  // prologue: stage tiles 0,1; wait tile 0 (3 newest stay in flight)
  STAGE(0, 0);
  STAGE(32, 1);
  SCHEDB();
  asm volatile("s_waitcnt vmcnt(3)" ::: "memory");
  __builtin_amdgcn_s_barrier();
  SCHEDB();

  int bcur = 0;
  for (int kt = 0; kt < K; kt += 32) {
    if (kt + 64 < K) {                       // stage tile t+2
      int bi = bcur + 2; if (bi >= 3) bi -= 3;
      STAGE(kt + 64, bi);
    }
    f16x8 af[4], bfr[4];
    #pragma unroll
    for (int mt = 0; mt < 4; ++mt)
      af[mt] = *(const f16x8*)&sh.ab.As[bcur][mh + mt * 16 + fm][colf];
    #pragma unroll
    for (int nt = 0; nt < 4; ++nt)
      bfr[nt] = *(const f16x8*)&sh.ab.Bs[bcur][nh + nt * 16 + fm][colf];
    __builtin_amdgcn_s_setprio(1);
    #pragma unroll
    for (int mt = 0; mt < 4; ++mt)
      #pragma unroll
      for (int nt = 0; nt < 4; ++nt)
        acc[mt][nt] = __builtin_amdgcn_mfma_f32_16x16x32_f16(
            af[mt], bfr[nt], acc[mt][nt], 0, 0, 0);
    __builtin_amdgcn_s_setprio(0);
    if (kt + 32 < K) {
      SCHEDB();
      if (kt + 64 < K)
        asm volatile("s_waitcnt vmcnt(3) lgkmcnt(0)" ::: "memory");
      else
        asm volatile("s_waitcnt vmcnt(0) lgkmcnt(0)" ::: "memory");  // tail
      __builtin_amdgcn_s_barrier();
      SCHEDB();
    }
    bcur = (bcur == 2) ? 0 : bcur + 1;
  }
  __syncthreads();   // full drain before Ep union reuse

  // ---- epilogue: 2 bands of 64 rows via Ep; frag row = fq*4+r, col = fm ----
  f16_t* Cd = Cd0 + (size_t)blockIdx.z * sC;
  #pragma unroll
  for (int p = 0; p < 2; ++p) {
    if (p) __syncthreads();
    if (wm == p) {
      #pragma unroll
      for (int mt = 0; mt < 4; ++mt) {
        float bv4[4];
        #pragma unroll
        for (int r = 0; r < 4; ++r)
          bv4[r] = bias[m0 + p * 64 + mt * 16 + fq * 4 + r];
        #pragma unroll
        for (int nt = 0; nt < 4; ++nt) {
          int col = nh + nt * 16 + fm;
          #pragma unroll
          for (int r = 0; r < 4; ++r) {
            int row = mt * 16 + fq * 4 + r;     // 0..63 within band
            sh.Ep[row][col] = (f16_t)(acc[mt][nt][r] + bv4[r]);
          }
        }
      }
    }
    __syncthreads();
    #pragma unroll
    for (int ii = 0; ii < 8; ++ii) {
      int chunk = ii * 512 + t;          // 4096 x 8B chunks, 64 rows x 64
      int row = chunk >> 6, c8 = chunk & 63;
      uint2 val = *(const uint2*)&sh.Ep[row][c8 * 4];
      *(uint2*)&Cd[(size_t)(m0 + p * 64 + row) * N + n0 + c8 * 4] = val;
    }
  }
}

// ---------------------------------------------------------------------------
// GEMM (output projection): 256x128 tile, BK=32, 512 thr / 8 waves (wave
// tile 64x64, acc[4][4]), 3-buffer counted-vmcnt pipeline, vmcnt(3) in-loop.
// IDENTITY block mapping (round-7 A/B closed the z-remap question: -2.5us).
// Final f32 out store stays NON-TEMPORAL: d_out is terminal (never re-read),
// evict-first frees L2/L3 capacity for woT/att2T during this kernel.
// ---------------------------------------------------------------------------
template <bool F32OUT, int K>
__global__ __launch_bounds__(512, 2) void _MSA1_kgemm(
    const f16_t* __restrict__ A, const f16_t* __restrict__ Bt,
    const float* __restrict__ bias, void* __restrict__ Cdv,
    int M, int N, long sA, long sB, long sC) {
  A  += (size_t)blockIdx.z * sA;
  Bt += (size_t)blockIdx.z * sB;
  const int m0 = blockIdx.y * 256, n0 = blockIdx.x * 128;

  union __align__(16) ShU {
    struct { f16_t As[3][256][32]; f16_t Bs[3][128][32]; } ab;  // 72 KB
    f16_t Ep[F32OUT ? 1 : 64][132];
  };
  __shared__ ShU sh;

  const int t = threadIdx.x;
  const int lane = t & 63, w = t >> 6;
  const int mh = (w & 3) * 64, nh = (w >> 2) * 64;
  const int fm = lane & 15, fq = lane >> 4;
  const int srcswz = ((t & 3) ^ ((t >> 2) & 3) ^ ((t >> 4) & 3)) * 8;
  const int colf = ((fq ^ (fm & 3) ^ ((fm >> 2) & 3)) * 8);

  floatx4 acc[4][4];
  #pragma unroll
  for (int i = 0; i < 4; ++i)
    #pragma unroll
    for (int j = 0; j < 4; ++j) {
      floatx4 z4 = {0.f, 0.f, 0.f, 0.f};
      acc[i][j] = z4;
    }

  auto STAGE = [&](int kt, int bi) {
    #pragma unroll
    for (int j = 0; j < 2; ++j) {                      // A: 256 rows, 16 KB
      int idx = j * 512 + t;
      int r = idx >> 2;
      const f16_t* ga = A + (size_t)(m0 + r) * K + kt + srcswz;
      __builtin_amdgcn_global_load_lds((gptr_as1)(const void*)ga,
          (lptr_as3)(void*)((char*)&sh.ab.As[bi][0][0] + idx * 16), 16, 0, 0);
    }
    {                                                  // B: 128 rows, 8 KB
      int r = t >> 2;
      const f16_t* gb = Bt + (size_t)(n0 + r) * K + kt + srcswz;
      __builtin_amdgcn_global_load_lds((gptr_as1)(const void*)gb,
          (lptr_as3)(void*)((char*)&sh.ab.Bs[bi][0][0] + t * 16), 16, 0, 0);
    }
  };

  STAGE(0, 0);
  STAGE(32, 1);
  SCHEDB();
  asm volatile("s_waitcnt vmcnt(3)" ::: "memory");
  __builtin_amdgcn_s_barrier();
  SCHEDB();

  int bcur = 0;
  for (int kt = 0; kt < K; kt += 32) {
    if (kt + 64 < K) {
      int bi = bcur + 2; if (bi >= 3) bi -= 3;
      STAGE(kt + 64, bi);
    }
    f16x8 af[4], bfr[4];
    #pragma unroll
    for (int mt = 0; mt < 4; ++mt)
      af[mt] = *(const f16x8*)&sh.ab.As[bcur][mh + mt * 16 + fm][colf];
    #pragma unroll
    for (int nt = 0; nt < 4; ++nt)
      bfr[nt] = *(const f16x8*)&sh.ab.Bs[bcur][nh + nt * 16 + fm][colf];
    __builtin_amdgcn_s_setprio(1);
    #pragma unroll
    for (int mt = 0; mt < 4; ++mt)
      #pragma unroll
      for (int nt = 0; nt < 4; ++nt)
        acc[mt][nt] = __builtin_amdgcn_mfma_f32_16x16x32_f16(
            af[mt], bfr[nt], acc[mt][nt], 0, 0, 0);
    __builtin_amdgcn_s_setprio(0);
    if (kt + 32 < K) {
      SCHEDB();
      if (kt + 64 < K)
        asm volatile("s_waitcnt vmcnt(3) lgkmcnt(0)" ::: "memory");
      else
        asm volatile("s_waitcnt vmcnt(0) lgkmcnt(0)" ::: "memory");
      __builtin_amdgcn_s_barrier();
      SCHEDB();
    }
    bcur = (bcur == 2) ? 0 : bcur + 1;
  }
  __syncthreads();

  if (F32OUT) {
    float* Cd = (float*)Cdv + (size_t)blockIdx.z * sC;
    #pragma unroll
    for (int mt = 0; mt < 4; ++mt) {
      float bv4[4];
      #pragma unroll
      for (int r = 0; r < 4; ++r)
        bv4[r] = bias[m0 + mh + mt * 16 + fq * 4 + r];
      #pragma unroll
      for (int nt = 0; nt < 4; ++nt) {
        int col = n0 + nh + nt * 16 + fm;
        #pragma unroll
        for (int r = 0; r < 4; ++r) {
          int row = m0 + mh + mt * 16 + fq * 4 + r;
          __builtin_nontemporal_store(acc[mt][nt][r] + bv4[r],
                                      &Cd[(size_t)row * N + col]);
        }
      }
    }
  } else {
    // (dead for current instantiations -- kept for template validity)
    f16_t* Cd = (f16_t*)Cdv + (size_t)blockIdx.z * sC;
    #pragma unroll
    for (int p = 0; p < 4; ++p) {
      if (p) __syncthreads();
      if ((w & 1) == (p >> 1)) {
        #pragma unroll
        for (int mt2 = 0; mt2 < 4; ++mt2) {
          float bv4[4];
          #pragma unroll
          for (int r = 0; r < 4; ++r)
            bv4[r] = bias[m0 + p * 64 + mt2 * 16 + fq * 4 + r];
          #pragma unroll
          for (int nt = 0; nt < 4; ++nt) {
            int col = nh + nt * 16 + fm;
            #pragma unroll
            for (int r = 0; r < 4; ++r) {
              int row = mt2 * 16 + fq * 4 + r;
              sh.Ep[row & (F32OUT ? 0 : 63)][col] = (f16_t)(acc[mt2][nt][r] + bv4[r]);
            }
          }
        }
      }
      __syncthreads();
      #pragma unroll
      for (int i = 0; i < 8; ++i) {
        int chunk = i * 256 + (t & 255);
        int row = chunk >> 5, c8 = chunk & 31;
        uint2 val = *(const uint2*)&sh.Ep[row & (F32OUT ? 0 : 63)][c8 * 4];
        *(uint2*)&Cd[(size_t)(m0 + p * 64 + row) * N + n0 + c8 * 4] = val;
      }
    }
  }
}

// ---------------------------------------------------------------------------
// Attention v6: merged interior+edge (per-lane predication), fused faithful-
// reshape transpose store.  Plain stores (att2T is consumed by the out-GEMM
// -- L3 residency matters, round-8 lesson).
// ---------------------------------------------------------------------------
__global__ __launch_bounds__(256) void _MSA1_kattn6(const f16_t* __restrict__ qkv,
                                                    f16_t* __restrict__ attT) {
  const int t = threadIdx.x;
  const int lane = t & 63;
  const int wid = __builtin_amdgcn_readfirstlane(t >> 6);
  const int hb = blockIdx.x;
  const int h = hb & 15, b = hb >> 4;
  const int chi = blockIdx.y;                 // l-chunk 0..7
  const int lbase = chi * 256;
  const int l0 = lbase + lane * 4;
  const size_t plane = (size_t)D_ * L_;
  const f16_t* base = qkv + (size_t)b * 3 * plane;

  __shared__ uint2 sred[4][3][64];
  __shared__ __align__(16) f16_t tile2[2048][8];

  const f16_t* qp = base + (size_t)(h * 64 + wid * 16) * L_ + l0;
  const f16_t* kpl = base + plane;
  const f16_t* vpl = base + 2 * plane;
  const int g0 = h * 192 + wid * 48;

  f16x2 sLo[3], sHi[3];
  #pragma unroll
  for (int w = 0; w < 3; ++w) { f16x2 z = {(f16_t)0, (f16_t)0}; sLo[w] = z; sHi[w] = z; }

  #pragma unroll
  for (int dd = 0; dd < 16; ++dd) {
    uint2 qw = *(const uint2*)(qp + (size_t)dd * L_);
    f16x2 qlo = bc2(qw.x), qhi = bc2(qw.y);
    #pragma unroll
    for (int w = 0; w < 3; ++w) {
      int g = g0 + 3 * dd + w;
      int c = g & 1023;
      int o = (g >> 10) - 1;
      uint2 kw = *(const uint2*)(kpl + (size_t)c * L_ + (l0 + o));
      if (o < 0 && l0 == 0) kw.x &= 0xFFFF0000u;
      if (o > 0 && l0 == 2044) kw.y &= 0x0000FFFFu;
      sLo[w] = bc2(kw.x) * qlo + sLo[w];
      sHi[w] = bc2(kw.y) * qhi + sHi[w];
    }
  }
  #pragma unroll
  for (int w = 0; w < 3; ++w) {
    uint2 v; v.x = cb2(sLo[w]); v.y = cb2(sHi[w]);
    sred[wid][w][lane] = v;
  }
  __syncthreads();

  float sc[4][3];
  #pragma unroll
  for (int j = 0; j < 3; ++j) {
    uint2 r0 = sred[0][j][lane], r1 = sred[1][j][lane];
    uint2 r2 = sred[2][j][lane], r3 = sred[3][j][lane];
    f16x2 lo = (bc2(r0.x) + bc2(r1.x)) + (bc2(r2.x) + bc2(r3.x));
    f16x2 hi = (bc2(r0.y) + bc2(r1.y)) + (bc2(r2.y) + bc2(r3.y));
    sc[0][j] = (float)lo.x * 0.125f;
    sc[1][j] = (float)lo.y * 0.125f;
    sc[2][j] = (float)hi.x * 0.125f;
    sc[3][j] = (float)hi.y * 0.125f;
  }
  f16_t ef[4][3];
  #pragma unroll
  for (int li = 0; li < 4; ++li) {
    float mx = fmaxf(sc[li][0], fmaxf(sc[li][1], sc[li][2]));
    float e0 = __expf(sc[li][0] - mx), e1 = __expf(sc[li][1] - mx), e2 = __expf(sc[li][2] - mx);
    float inv = 1.f / (e0 + e1 + e2);
    ef[li][0] = (f16_t)(e0 * inv); ef[li][1] = (f16_t)(e1 * inv); ef[li][2] = (f16_t)(e2 * inv);
  }
  f16x2 eLo[3], eHi[3];
  #pragma unroll
  for (int w = 0; w < 3; ++w) {
    f16x2 a = {ef[0][w], ef[1][w]}; eLo[w] = a;
    f16x2 b2 = {ef[2][w], ef[3][w]}; eHi[w] = b2;
  }

  const int llb = (lane & 7) * 256 + wid * 16;
  const int jcol = lane >> 3;
  #pragma unroll
  for (int dd = 0; dd < 16; ++dd) {
    f16x2 aLo = {(f16_t)0, (f16_t)0}, aHi = {(f16_t)0, (f16_t)0};
    #pragma unroll
    for (int w = 0; w < 3; ++w) {
      int g = g0 + 3 * dd + w;
      int c = g & 1023;
      int o = (g >> 10) - 1;
      uint2 vw = *(const uint2*)(vpl + (size_t)c * L_ + (l0 + o));
      if (o < 0 && l0 == 0) vw.x &= 0xFFFF0000u;
      if (o > 0 && l0 == 2044) vw.y &= 0x0000FFFFu;
      aLo = bc2(vw.x) * eLo[w] + aLo;
      aHi = bc2(vw.y) * eHi[w] + aHi;
    }
    const int llq = llb + dd;
    tile2[llq +   0][jcol] = aLo.x;
    tile2[llq +  64][jcol] = aLo.y;
    tile2[llq + 128][jcol] = aHi.x;
    tile2[llq + 192][jcol] = aHi.y;
  }
  __syncthreads();

  f16_t* ob = attT + (size_t)b * L_ * D_ + h * 64 + chi * 8;
  #pragma unroll
  for (int i = 0; i < 8; ++i) {
    int ll = i * 256 + t;
    uint4 val = *(const uint4*)&tile2[ll][0];
    *(uint4*)(ob + (size_t)ll * D_) = val;
  }
}

// ---------------------------------------------------------------------------
extern "C" void kernel_launch(void* const* d_in, const int* in_sizes, int n_in,
                              void* d_out, int out_size, void* d_ws, size_t ws_size,
                              hipStream_t stream) {
  (void)in_sizes; (void)n_in; (void)out_size;
  const float* x  = (const float*)d_in[0];
  const float* wq = (const float*)d_in[1];
  const float* bq = (const float*)d_in[2];
  const float* wk = (const float*)d_in[3];
  const float* bk = (const float*)d_in[4];
  const float* wv = (const float*)d_in[5];
  const float* bv = (const float*)d_in[6];
  const float* wo = (const float*)d_in[7];
  const float* bo = (const float*)d_in[8];
  float* out = (float*)d_out;
  char* ws = (char*)d_ws;

  f16_t* wT3   = (f16_t*)(ws);                 // 3x(1024x512) f16 = 3,145,728 B
  f16_t* woT   = (f16_t*)(ws + 3145728);       // (512x1024)  f16 = 1,048,576 B
  float* bias3 = (float*) (ws + 4194304);      // 3072 f32 (pad to 16,384)
  const size_t SHARED_END = 4210688;

  _MSA1_kprep<<<dim3(129, 4), dim3(256), 0, stream>>>(
      wq, wk, wv, wo, bq, bk, bv, wT3, woT, bias3);

  if (ws_size >= 155205632ull) {
    // ---------- batched-z path: xT 16.7MB + qkv 100.7MB + att2T 33.5MB ----
    f16_t* xT    = (f16_t*)(ws + SHARED_END);
    f16_t* qkv   = xT + 8388608ull;
    f16_t* att2T = qkv + 50331648ull;

    _MSA1_ktransf2h<<<dim3(32, 8, B_), dim3(256), 0, stream>>>(x, xT, 512, 2048);
    _MSA1_kgemm8<512><<<dim3(8, 24, B_), dim3(512), 0, stream>>>(
        wT3, xT, bias3, qkv, 3072, 2048,
        (long)(2048 * 512), (long)(3072 * 2048));
    _MSA1_kattn6<<<dim3(128, 8), dim3(256), 0, stream>>>(qkv, att2T);
    _MSA1_kgemm<true, 1024><<<dim3(16, 2, B_), dim3(512), 0, stream>>>(
        woT, att2T, bo, out, 512, 2048,
        0L, (long)(2048 * 1024), (long)(512 * 2048));
  } else {
    // ---------- per-batch slab path ----------
    f16_t* xTb    = (f16_t*)(ws + SHARED_END);
    f16_t* qkvb   = xTb + 1048576ull;
    f16_t* att2Tb = qkvb + 6291456ull;
    for (int b = 0; b < B_; ++b) {
      const float* xb = x + (size_t)b * C_ * L_;
      _MSA1_ktransf2h<<<dim3(32, 8, 1), dim3(256), 0, stream>>>(xb, xTb, 512, 2048);
      _MSA1_kgemm8<512><<<dim3(8, 24, 1), dim3(512), 0, stream>>>(
          wT3, xTb, bias3, qkvb, 3072, 2048, 0L, 0L);
      _MSA1_kattn6<<<dim3(16, 8), dim3(256), 0, stream>>>(qkvb, att2Tb);
      _MSA1_kgemm<true, 1024><<<dim3(16, 2, 1), dim3(512), 0, stream>>>(
          woT, att2Tb, bo, out + (size_t)b * C_ * L_, 512, 2048, 0L, 0L, 0L);
    }
  }
}

// Round 10
// 253.212 us; speedup vs baseline: 1.2535x; 1.0184x over previous
//
#include <hip/hip_runtime.h>

typedef _Float16 f16_t;
typedef _Float16 f16x2 __attribute__((ext_vector_type(2)));
typedef _Float16 f16x8 __attribute__((ext_vector_type(8)));
typedef float floatx4 __attribute__((ext_vector_type(4)));
typedef unsigned int u32;
typedef const __attribute__((address_space(1))) unsigned int* gptr_as1;
typedef __attribute__((address_space(3))) unsigned int* lptr_as3;

#define B_ 8
#define C_ 512
#define L_ 2048
#define D_ 1024
#define H_ 16

static __device__ __forceinline__ f16x2 bc2(u32 v) { return __builtin_bit_cast(f16x2, v); }
static __device__ __forceinline__ u32 cb2(f16x2 v) { return __builtin_bit_cast(u32, v); }

#define SCHEDB() __builtin_amdgcn_sched_barrier(0)

// ---------------------------------------------------------------------------
// Transpose + f32->f16 convert: in (R,C) f32 -> out (C,R) f16, batched z.
// ---------------------------------------------------------------------------
__global__ __launch_bounds__(256) void _MSA1_ktransf2h(const float* __restrict__ in,
                                                       f16_t* __restrict__ out,
                                                       int R, int C) {
  size_t zoff = (size_t)blockIdx.z * R * C;
  in += zoff; out += zoff;
  __shared__ f16_t tile[64][65];
  int r0 = blockIdx.y * 64, c0 = blockIdx.x * 64;
  int t = threadIdx.x;
  #pragma unroll
  for (int i = 0; i < 16; ++i) {
    int idx = t + i * 256;
    int r = idx >> 6, c = idx & 63;
    tile[c][r] = (f16_t)in[(size_t)(r0 + r) * C + (c0 + c)];
  }
  __syncthreads();
  #pragma unroll
  for (int i = 0; i < 16; ++i) {
    int idx = t + i * 256;
    int r = idx >> 6, c = idx & 63;
    out[(size_t)(c0 + r) * R + (r0 + c)] = tile[r][c];
  }
}

// ---------------------------------------------------------------------------
// Fused prep: all 4 weight transposes (f32->f16) + bias concat, one launch.
// ---------------------------------------------------------------------------
__global__ __launch_bounds__(256) void _MSA1_kprep(
    const float* __restrict__ wq, const float* __restrict__ wk,
    const float* __restrict__ wv, const float* __restrict__ wo,
    const float* __restrict__ bq, const float* __restrict__ bk,
    const float* __restrict__ bv,
    f16_t* __restrict__ wT3, f16_t* __restrict__ woT, float* __restrict__ bias3) {
  const int x = blockIdx.x, y = blockIdx.y;
  const int t = threadIdx.x;
  if (x == 128) {
    if (y == 0) {
      for (int i = t; i < 1024; i += 256) {
        bias3[i] = bq[i];
        bias3[1024 + i] = bk[i];
        bias3[2048 + i] = bv[i];
      }
    }
    return;
  }
  __shared__ f16_t tile[64][65];
  const float* in; f16_t* out; int R, C, r0, c0;
  if (y < 3) {
    R = 512; C = 1024;
    in = (y == 0) ? wq : (y == 1) ? wk : wv;
    out = wT3 + (size_t)y * 524288;
    r0 = (x >> 4) * 64; c0 = (x & 15) * 64;
  } else {
    R = 1024; C = 512;
    in = wo; out = woT;
    r0 = (x >> 3) * 64; c0 = (x & 7) * 64;
  }
  #pragma unroll
  for (int i = 0; i < 16; ++i) {
    int idx = t + i * 256;
    int r = idx >> 6, c = idx & 63;
    tile[c][r] = (f16_t)in[(size_t)(r0 + r) * C + (c0 + c)];
  }
  __syncthreads();
  #pragma unroll
  for (int i = 0; i < 16; ++i) {
    int idx = t + i * 256;
    int r = idx >> 6, c = idx & 63;
    out[(size_t)(c0 + r) * R + (r0 + c)] = tile[r][c];
  }
}

// ---------------------------------------------------------------------------
// kgemm8 (QKV) v10: round-6 protocol, tile SWAPPED to BM=256, BN=128.
// 512 thr (8 waves 4Mx2N, wave tile 64x64 acc[4][4]), BK=32, 3 LDS buffers
// (72 KB), STAGE(i+2) at top of iter i, in-loop wait vmcnt(3)+lgkmcnt(0),
// vmcnt(0) only at tail, sched_barrier(0) fences.  IDENTITY block mapping.
// Why swap: BM=128/BN=256 re-staged the BIG tensor (xT 16.8MB) 24x (394MB of
// the 590MB staged) -> 69MB HBM refetch.  BM=256/BN=128 halves B-redundancy
// to 12x; A (wT3, 3MB) becomes the redundant one but it's L2-resident, so
// its refetches are L2 hits.  Per-XCD instantaneous working set drops
// ~5MB -> ~2MB (< 4MB L2).  Protocol constants unchanged (3 DMA ops/stage).
// Closed questions (do NOT re-try): nt-on-qkv (round-8, -63us catastrophe),
// nt-on-out (round-9, +3.9us), 2-buf/48KB (round-7), z-per-XCD remap
// (rounds 5/7), 4-phase 256^2 @1 block/CU (round 4).
// ---------------------------------------------------------------------------
template <int K>
__global__ __launch_bounds__(512, 4) void _MSA1_kgemm8(
    const f16_t* __restrict__ A, const f16_t* __restrict__ Bt,
    const float* __restrict__ bias, f16_t* __restrict__ Cd0,
    int M, int N, long sB, long sC) {
  const f16_t* Bz = Bt + (size_t)blockIdx.z * sB;
  const int m0 = blockIdx.y * 256, n0 = blockIdx.x * 128;

  union __align__(16) ShU {
    struct { f16_t As[3][256][32]; f16_t Bs[3][128][32]; } ab;  // 72 KB
    f16_t Ep[64][132];                                           // 16.9 KB
  };
  __shared__ ShU sh;

  const int t = threadIdx.x;
  const int lane = t & 63, w = t >> 6;
  const int wm = w & 3;                       // 4 M-waves
  const int mh = wm * 64, nh = (w >> 2) * 64; // 2 N-waves
  const int fm = lane & 15, fq = lane >> 4;
  // staging source pre-swizzle: slot = (lane&3) ^ (r&3) ^ ((r>>2)&3)
  const int srcswz = ((t & 3) ^ ((t >> 2) & 3) ^ ((t >> 4) & 3)) * 8;
  // frag-read column swizzle: R&3 = fm&3, (R>>2)&3 = (fm>>2)&3  ->  slot fq
  const int colf = ((fq ^ (fm & 3) ^ ((fm >> 2) & 3)) * 8);

  floatx4 acc[4][4];
  #pragma unroll
  for (int i = 0; i < 4; ++i)
    #pragma unroll
    for (int j = 0; j < 4; ++j) {
      floatx4 z4 = {0.f, 0.f, 0.f, 0.f};
      acc[i][j] = z4;
    }

  auto STAGE = [&](int kt, int bi) {
    #pragma unroll
    for (int j = 0; j < 2; ++j) {                      // A: 256 rows, 16 KB
      int idx = j * 512 + t;
      int r = idx >> 2;
      const f16_t* ga = A + (size_t)(m0 + r) * K + kt + srcswz;
      __builtin_amdgcn_global_load_lds((gptr_as1)(const void*)ga,
          (lptr_as3)(void*)((char*)&sh.ab.As[bi][0][0] + idx * 16), 16, 0, 0);
    }
    {                                                  // B: 128 rows, 8 KB
      int r = t >> 2;
      const f16_t* gb = Bz + (size_t)(n0 + r) * K + kt + srcswz;
      __builtin_amdgcn_global_load_lds((gptr_as1)(const void*)gb,
          (lptr_as3)(void*)((char*)&sh.ab.Bs[bi][0][0] + t * 16), 16, 0, 0);
    }
  };

  // prologue: stage tiles 0,1; wait tile 0 (3 newest stay in flight)
  STAGE(0, 0);
  STAGE(32, 1);
  SCHEDB();
  asm volatile("s_waitcnt vmcnt(3)" ::: "memory");
  __builtin_amdgcn_s_barrier();
  SCHEDB();

  int bcur = 0;
  for (int kt = 0; kt < K; kt += 32) {
    if (kt + 64 < K) {                       // stage tile t+2
      int bi = bcur + 2; if (bi >= 3) bi -= 3;
      STAGE(kt + 64, bi);
    }
    f16x8 af[4], bfr[4];
    #pragma unroll
    for (int mt = 0; mt < 4; ++mt)
      af[mt] = *(const f16x8*)&sh.ab.As[bcur][mh + mt * 16 + fm][colf];
    #pragma unroll
    for (int nt = 0; nt < 4; ++nt)
      bfr[nt] = *(const f16x8*)&sh.ab.Bs[bcur][nh + nt * 16 + fm][colf];
    __builtin_amdgcn_s_setprio(1);
    #pragma unroll
    for (int mt = 0; mt < 4; ++mt)
      #pragma unroll
      for (int nt = 0; nt < 4; ++nt)
        acc[mt][nt] = __builtin_amdgcn_mfma_f32_16x16x32_f16(
            af[mt], bfr[nt], acc[mt][nt], 0, 0, 0);
    __builtin_amdgcn_s_setprio(0);
    if (kt + 32 < K) {
      SCHEDB();
      if (kt + 64 < K)
        asm volatile("s_waitcnt vmcnt(3) lgkmcnt(0)" ::: "memory");
      else
        asm volatile("s_waitcnt vmcnt(0) lgkmcnt(0)" ::: "memory");  // tail
      __builtin_amdgcn_s_barrier();
      SCHEDB();
    }
    bcur = (bcur == 2) ? 0 : bcur + 1;
  }
  __syncthreads();   // full drain before Ep union reuse

  // ---- epilogue: 4 bands of 64 rows via Ep; frag row = fq*4+r, col = fm ----
  // Band p = tile rows [64p, 64p+64), owned by the 2 waves with wm == p
  // (their nh 0/64 cover the 128 cols).
  f16_t* Cd = Cd0 + (size_t)blockIdx.z * sC;
  #pragma unroll
  for (int p = 0; p < 4; ++p) {
    if (p) __syncthreads();
    if (wm == p) {
      #pragma unroll
      for (int mt = 0; mt < 4; ++mt) {
        float bv4[4];
        #pragma unroll
        for (int r = 0; r < 4; ++r)
          bv4[r] = bias[m0 + p * 64 + mt * 16 + fq * 4 + r];
        #pragma unroll
        for (int nt = 0; nt < 4; ++nt) {
          int col = nh + nt * 16 + fm;
          #pragma unroll
          for (int r = 0; r < 4; ++r) {
            int row = mt * 16 + fq * 4 + r;     // 0..63 within band
            sh.Ep[row][col] = (f16_t)(acc[mt][nt][r] + bv4[r]);
          }
        }
      }
    }
    __syncthreads();
    #pragma unroll
    for (int ii = 0; ii < 4; ++ii) {
      int chunk = ii * 512 + t;          // 2048 x 8B chunks, 64 rows x 32
      int row = chunk >> 5, c8 = chunk & 31;
      uint2 val = *(const uint2*)&sh.Ep[row][c8 * 4];
      *(uint2*)&Cd[(size_t)(m0 + p * 64 + row) * N + n0 + c8 * 4] = val;
    }
  }
}

// ---------------------------------------------------------------------------
// GEMM (output projection): 256x128 tile, BK=32, 512 thr / 8 waves (wave
// tile 64x64, acc[4][4]), 3-buffer counted-vmcnt pipeline, vmcnt(3) in-loop.
// IDENTITY block mapping.  Plain f32 stores (round-9: nt was +3.9us).
// ---------------------------------------------------------------------------
template <bool F32OUT, int K>
__global__ __launch_bounds__(512, 2) void _MSA1_kgemm(
    const f16_t* __restrict__ A, const f16_t* __restrict__ Bt,
    const float* __restrict__ bias, void* __restrict__ Cdv,
    int M, int N, long sA, long sB, long sC) {
  A  += (size_t)blockIdx.z * sA;
  Bt += (size_t)blockIdx.z * sB;
  const int m0 = blockIdx.y * 256, n0 = blockIdx.x * 128;

  union __align__(16) ShU {
    struct { f16_t As[3][256][32]; f16_t Bs[3][128][32]; } ab;  // 72 KB
    f16_t Ep[F32OUT ? 1 : 64][132];
  };
  __shared__ ShU sh;

  const int t = threadIdx.x;
  const int lane = t & 63, w = t >> 6;
  const int mh = (w & 3) * 64, nh = (w >> 2) * 64;
  const int fm = lane & 15, fq = lane >> 4;
  const int srcswz = ((t & 3) ^ ((t >> 2) & 3) ^ ((t >> 4) & 3)) * 8;
  const int colf = ((fq ^ (fm & 3) ^ ((fm >> 2) & 3)) * 8);

  floatx4 acc[4][4];
  #pragma unroll
  for (int i = 0; i < 4; ++i)
    #pragma unroll
    for (int j = 0; j < 4; ++j) {
      floatx4 z4 = {0.f, 0.f, 0.f, 0.f};
      acc[i][j] = z4;
    }

  auto STAGE = [&](int kt, int bi) {
    #pragma unroll
    for (int j = 0; j < 2; ++j) {                      // A: 256 rows, 16 KB
      int idx = j * 512 + t;
      int r = idx >> 2;
      const f16_t* ga = A + (size_t)(m0 + r) * K + kt + srcswz;
      __builtin_amdgcn_global_load_lds((gptr_as1)(const void*)ga,
          (lptr_as3)(void*)((char*)&sh.ab.As[bi][0][0] + idx * 16), 16, 0, 0);
    }
    {                                                  // B: 128 rows, 8 KB
      int r = t >> 2;
      const f16_t* gb = Bt + (size_t)(n0 + r) * K + kt + srcswz;
      __builtin_amdgcn_global_load_lds((gptr_as1)(const void*)gb,
          (lptr_as3)(void*)((char*)&sh.ab.Bs[bi][0][0] + t * 16), 16, 0, 0);
    }
  };

  STAGE(0, 0);
  STAGE(32, 1);
  SCHEDB();
  asm volatile("s_waitcnt vmcnt(3)" ::: "memory");
  __builtin_amdgcn_s_barrier();
  SCHEDB();

  int bcur = 0;
  for (int kt = 0; kt < K; kt += 32) {
    if (kt + 64 < K) {
      int bi = bcur + 2; if (bi >= 3) bi -= 3;
      STAGE(kt + 64, bi);
    }
    f16x8 af[4], bfr[4];
    #pragma unroll
    for (int mt = 0; mt < 4; ++mt)
      af[mt] = *(const f16x8*)&sh.ab.As[bcur][mh + mt * 16 + fm][colf];
    #pragma unroll
    for (int nt = 0; nt < 4; ++nt)
      bfr[nt] = *(const f16x8*)&sh.ab.Bs[bcur][nh + nt * 16 + fm][colf];
    __builtin_amdgcn_s_setprio(1);
    #pragma unroll
    for (int mt = 0; mt < 4; ++mt)
      #pragma unroll
      for (int nt = 0; nt < 4; ++nt)
        acc[mt][nt] = __builtin_amdgcn_mfma_f32_16x16x32_f16(
            af[mt], bfr[nt], acc[mt][nt], 0, 0, 0);
    __builtin_amdgcn_s_setprio(0);
    if (kt + 32 < K) {
      SCHEDB();
      if (kt + 64 < K)
        asm volatile("s_waitcnt vmcnt(3) lgkmcnt(0)" ::: "memory");
      else
        asm volatile("s_waitcnt vmcnt(0) lgkmcnt(0)" ::: "memory");
      __builtin_amdgcn_s_barrier();
      SCHEDB();
    }
    bcur = (bcur == 2) ? 0 : bcur + 1;
  }
  __syncthreads();

  if (F32OUT) {
    float* Cd = (float*)Cdv + (size_t)blockIdx.z * sC;
    #pragma unroll
    for (int mt = 0; mt < 4; ++mt) {
      float bv4[4];
      #pragma unroll
      for (int r = 0; r < 4; ++r)
        bv4[r] = bias[m0 + mh + mt * 16 + fq * 4 + r];
      #pragma unroll
      for (int nt = 0; nt < 4; ++nt) {
        int col = n0 + nh + nt * 16 + fm;
        #pragma unroll
        for (int r = 0; r < 4; ++r) {
          int row = m0 + mh + mt * 16 + fq * 4 + r;
          Cd[(size_t)row * N + col] = acc[mt][nt][r] + bv4[r];
        }
      }
    }
  } else {
    // (dead for current instantiations -- kept for template validity)
    f16_t* Cd = (f16_t*)Cdv + (size_t)blockIdx.z * sC;
    #pragma unroll
    for (int p = 0; p < 4; ++p) {
      if (p) __syncthreads();
      if ((w & 1) == (p >> 1)) {
        #pragma unroll
        for (int mt2 = 0; mt2 < 4; ++mt2) {
          float bv4[4];
          #pragma unroll
          for (int r = 0; r < 4; ++r)
            bv4[r] = bias[m0 + p * 64 + mt2 * 16 + fq * 4 + r];
          #pragma unroll
          for (int nt = 0; nt < 4; ++nt) {
            int col = nh + nt * 16 + fm;
            #pragma unroll
            for (int r = 0; r < 4; ++r) {
              int row = mt2 * 16 + fq * 4 + r;
              sh.Ep[row & (F32OUT ? 0 : 63)][col] = (f16_t)(acc[mt2][nt][r] + bv4[r]);
            }
          }
        }
      }
      __syncthreads();
      #pragma unroll
      for (int i = 0; i < 8; ++i) {
        int chunk = i * 256 + (t & 255);
        int row = chunk >> 5, c8 = chunk & 31;
        uint2 val = *(const uint2*)&sh.Ep[row & (F32OUT ? 0 : 63)][c8 * 4];
        *(uint2*)&Cd[(size_t)(m0 + p * 64 + row) * N + n0 + c8 * 4] = val;
      }
    }
  }
}

// ---------------------------------------------------------------------------
// Attention v6: merged interior+edge (per-lane predication), fused faithful-
// reshape transpose store.  Plain stores (att2T is consumed by the out-GEMM
// -- L3 residency matters, round-8 lesson).
// ---------------------------------------------------------------------------
__global__ __launch_bounds__(256) void _MSA1_kattn6(const f16_t* __restrict__ qkv,
                                                    f16_t* __restrict__ attT) {
  const int t = threadIdx.x;
  const int lane = t & 63;
  const int wid = __builtin_amdgcn_readfirstlane(t >> 6);
  const int hb = blockIdx.x;
  const int h = hb & 15, b = hb >> 4;
  const int chi = blockIdx.y;                 // l-chunk 0..7
  const int lbase = chi * 256;
  const int l0 = lbase + lane * 4;
  const size_t plane = (size_t)D_ * L_;
  const f16_t* base = qkv + (size_t)b * 3 * plane;

  __shared__ uint2 sred[4][3][64];
  __shared__ __align__(16) f16_t tile2[2048][8];

  const f16_t* qp = base + (size_t)(h * 64 + wid * 16) * L_ + l0;
  const f16_t* kpl = base + plane;
  const f16_t* vpl = base + 2 * plane;
  const int g0 = h * 192 + wid * 48;

  f16x2 sLo[3], sHi[3];
  #pragma unroll
  for (int w = 0; w < 3; ++w) { f16x2 z = {(f16_t)0, (f16_t)0}; sLo[w] = z; sHi[w] = z; }

  #pragma unroll
  for (int dd = 0; dd < 16; ++dd) {
    uint2 qw = *(const uint2*)(qp + (size_t)dd * L_);
    f16x2 qlo = bc2(qw.x), qhi = bc2(qw.y);
    #pragma unroll
    for (int w = 0; w < 3; ++w) {
      int g = g0 + 3 * dd + w;
      int c = g & 1023;
      int o = (g >> 10) - 1;
      uint2 kw = *(const uint2*)(kpl + (size_t)c * L_ + (l0 + o));
      if (o < 0 && l0 == 0) kw.x &= 0xFFFF0000u;
      if (o > 0 && l0 == 2044) kw.y &= 0x0000FFFFu;
      sLo[w] = bc2(kw.x) * qlo + sLo[w];
      sHi[w] = bc2(kw.y) * qhi + sHi[w];
    }
  }
  #pragma unroll
  for (int w = 0; w < 3; ++w) {
    uint2 v; v.x = cb2(sLo[w]); v.y = cb2(sHi[w]);
    sred[wid][w][lane] = v;
  }
  __syncthreads();

  float sc[4][3];
  #pragma unroll
  for (int j = 0; j < 3; ++j) {
    uint2 r0 = sred[0][j][lane], r1 = sred[1][j][lane];
    uint2 r2 = sred[2][j][lane], r3 = sred[3][j][lane];
    f16x2 lo = (bc2(r0.x) + bc2(r1.x)) + (bc2(r2.x) + bc2(r3.x));
    f16x2 hi = (bc2(r0.y) + bc2(r1.y)) + (bc2(r2.y) + bc2(r3.y));
    sc[0][j] = (float)lo.x * 0.125f;
    sc[1][j] = (float)lo.y * 0.125f;
    sc[2][j] = (float)hi.x * 0.125f;
    sc[3][j] = (float)hi.y * 0.125f;
  }
  f16_t ef[4][3];
  #pragma unroll
  for (int li = 0; li < 4; ++li) {
    float mx = fmaxf(sc[li][0], fmaxf(sc[li][1], sc[li][2]));
    float e0 = __expf(sc[li][0] - mx), e1 = __expf(sc[li][1] - mx), e2 = __expf(sc[li][2] - mx);
    float inv = 1.f / (e0 + e1 + e2);
    ef[li][0] = (f16_t)(e0 * inv); ef[li][1] = (f16_t)(e1 * inv); ef[li][2] = (f16_t)(e2 * inv);
  }
  f16x2 eLo[3], eHi[3];
  #pragma unroll
  for (int w = 0; w < 3; ++w) {
    f16x2 a = {ef[0][w], ef[1][w]}; eLo[w] = a;
    f16x2 b2 = {ef[2][w], ef[3][w]}; eHi[w] = b2;
  }

  const int llb = (lane & 7) * 256 + wid * 16;
  const int jcol = lane >> 3;
  #pragma unroll
  for (int dd = 0; dd < 16; ++dd) {
    f16x2 aLo = {(f16_t)0, (f16_t)0}, aHi = {(f16_t)0, (f16_t)0};
    #pragma unroll
    for (int w = 0; w < 3; ++w) {
      int g = g0 + 3 * dd + w;
      int c = g & 1023;
      int o = (g >> 10) - 1;
      uint2 vw = *(const uint2*)(vpl + (size_t)c * L_ + (l0 + o));
      if (o < 0 && l0 == 0) vw.x &= 0xFFFF0000u;
      if (o > 0 && l0 == 2044) vw.y &= 0x0000FFFFu;
      aLo = bc2(vw.x) * eLo[w] + aLo;
      aHi = bc2(vw.y) * eHi[w] + aHi;
    }
    const int llq = llb + dd;
    tile2[llq +   0][jcol] = aLo.x;
    tile2[llq +  64][jcol] = aLo.y;
    tile2[llq + 128][jcol] = aHi.x;
    tile2[llq + 192][jcol] = aHi.y;
  }
  __syncthreads();

  f16_t* ob = attT + (size_t)b * L_ * D_ + h * 64 + chi * 8;
  #pragma unroll
  for (int i = 0; i < 8; ++i) {
    int ll = i * 256 + t;
    uint4 val = *(const uint4*)&tile2[ll][0];
    *(uint4*)(ob + (size_t)ll * D_) = val;
  }
}

// ---------------------------------------------------------------------------
extern "C" void kernel_launch(void* const* d_in, const int* in_sizes, int n_in,
                              void* d_out, int out_size, void* d_ws, size_t ws_size,
                              hipStream_t stream) {
  (void)in_sizes; (void)n_in; (void)out_size;
  const float* x  = (const float*)d_in[0];
  const float* wq = (const float*)d_in[1];
  const float* bq = (const float*)d_in[2];
  const float* wk = (const float*)d_in[3];
  const float* bk = (const float*)d_in[4];
  const float* wv = (const float*)d_in[5];
  const float* bv = (const float*)d_in[6];
  const float* wo = (const float*)d_in[7];
  const float* bo = (const float*)d_in[8];
  float* out = (float*)d_out;
  char* ws = (char*)d_ws;

  f16_t* wT3   = (f16_t*)(ws);                 // 3x(1024x512) f16 = 3,145,728 B
  f16_t* woT   = (f16_t*)(ws + 3145728);       // (512x1024)  f16 = 1,048,576 B
  float* bias3 = (float*) (ws + 4194304);      // 3072 f32 (pad to 16,384)
  const size_t SHARED_END = 4210688;

  _MSA1_kprep<<<dim3(129, 4), dim3(256), 0, stream>>>(
      wq, wk, wv, wo, bq, bk, bv, wT3, woT, bias3);

  if (ws_size >= 155205632ull) {
    // ---------- batched-z path: xT 16.7MB + qkv 100.7MB + att2T 33.5MB ----
    f16_t* xT    = (f16_t*)(ws + SHARED_END);
    f16_t* qkv   = xT + 8388608ull;
    f16_t* att2T = qkv + 50331648ull;

    _MSA1_ktransf2h<<<dim3(32, 8, B_), dim3(256), 0, stream>>>(x, xT, 512, 2048);
    _MSA1_kgemm8<512><<<dim3(16, 12, B_), dim3(512), 0, stream>>>(
        wT3, xT, bias3, qkv, 3072, 2048,
        (long)(2048 * 512), (long)(3072 * 2048));
    _MSA1_kattn6<<<dim3(128, 8), dim3(256), 0, stream>>>(qkv, att2T);
    _MSA1_kgemm<true, 1024><<<dim3(16, 2, B_), dim3(512), 0, stream>>>(
        woT, att2T, bo, out, 512, 2048,
        0L, (long)(2048 * 1024), (long)(512 * 2048));
  } else {
    // ---------- per-batch slab path ----------
    f16_t* xTb    = (f16_t*)(ws + SHARED_END);
    f16_t* qkvb   = xTb + 1048576ull;
    f16_t* att2Tb = qkvb + 6291456ull;
    for (int b = 0; b < B_; ++b) {
      const float* xb = x + (size_t)b * C_ * L_;
      _MSA1_ktransf2h<<<dim3(32, 8, 1), dim3(256), 0, stream>>>(xb, xTb, 512, 2048);
      _MSA1_kgemm8<512><<<dim3(16, 12, 1), dim3(512), 0, stream>>>(
          wT3, xTb, bias3, qkvb, 3072, 2048, 0L, 0L);
      _MSA1_kattn6<<<dim3(16, 8), dim3(256), 0, stream>>>(qkvb, att2Tb);
      _MSA1_kgemm<true, 1024><<<dim3(16, 2, 1), dim3(512), 0, stream>>>(
          woT, att2Tb, bo, out + (size_t)b * C_ * L_, 512, 2048, 0L, 0L, 0L);
    }
  }
}